// Round 4
// baseline (241.846 us; speedup 1.0000x reference)
//
#include <hip/hip_runtime.h>
#include <hip/hip_fp16.h>

#define BB 4
#define CC 3
#define HH 384
#define WW 384
#define HW (HH * WW)
#define KK 5
#define RR 2
#define K2 25
#define NITER 20
#define PADF 2048   // guard floats around each x buffer (max OOB reach is 772)

static constexpr float INV_Z2 = 1.0f / (0.15f * 0.15f);

// ---------------------------------------------------------------------------
// prep: 2 px/thread. Per-pixel 5x5 normalized affinity, WITH mask(p) folded
// in (exact identity: x_{k+1}(p) = mask(p)*sum w*x = sum (mask(p)*w)*x), so
// iteration kernels never touch mask. fp16 planes wgt[b][t][pix];
// x0 = feat*mask. OOB taps are exactly 0 (+10 shift -> exp underflow), so
// iter kernels read x branch-free through padded guards.
// ---------------------------------------------------------------------------
__global__ __launch_bounds__(256) void prep2(
    const float* __restrict__ img, const float* __restrict__ feat,
    const float* __restrict__ mask, __half* __restrict__ wgt,
    float* __restrict__ x0)
{
    int gid = blockIdx.x * 256 + threadIdx.x;
    int p0 = gid * 2;
    if (p0 >= BB * HW) return;
    int b   = p0 / HW;
    int rem = p0 - b * HW;          // even
    int h   = rem / WW;
    int wc  = rem - h * WW;

    const float* imgb = img + (size_t)b * CC * HW;
    const size_t bHW = (size_t)b * HW;

    float2 f  = *(const float2*)(feat + bHW + rem);
    float2 mk = *(const float2*)(mask + bHW + rem);
    *(float2*)(x0 + bHW + rem) = make_float2(f.x * mk.x, f.y * mk.y);

    float v0[2], v1[2], v2[2];
#pragma unroll
    for (int s = 0; s < 2; ++s) {
        v0[s] = imgb[0 * HW + rem + s] + 10.f;
        v1[s] = imgb[1 * HW + rem + s] + 10.f;
        v2[s] = imgb[2 * HW + rem + s] + 10.f;
    }

    float a[2][K2];
    float sz[2] = {1e-10f, 1e-10f};
#pragma unroll
    for (int t = 0; t < K2; ++t) {
        int dr = t / KK - RR, dc = t % KK - RR;
        int rr = h + dr;
#pragma unroll
        for (int s = 0; s < 2; ++s) {
            int cc2 = wc + s + dc;
            float av = 0.f;
            if (rr >= 0 && rr < HH && cc2 >= 0 && cc2 < WW) {
                int q = rr * WW + cc2;
                float d0 = imgb[0 * HW + q] + 10.f - v0[s];
                float d1 = imgb[1 * HW + q] + 10.f - v1[s];
                float d2 = imgb[2 * HW + q] + 10.f - v2[s];
                av = __expf(-(d0 * d0 + d1 * d1 + d2 * d2) * INV_Z2);
            }
            a[s][t] = av;
            sz[s] += av;
        }
    }
    float i0 = mk.x / sz[0], i1 = mk.y / sz[1];   // mask folded into weights
#pragma unroll
    for (int t = 0; t < K2; ++t) {
        __half2 hv = __floats2half2_rn(a[0][t] * i0, a[1][t] * i1);
        *(__half2*)(wgt + ((size_t)b * K2 + t) * HW + rem) = hv;
    }
}

// ---------------------------------------------------------------------------
// One iteration, 4 px/thread (576 blocks -> 9 waves/CU for latency hiding).
// Branch-free: OOB x reads land in guard pads / adjacent rows and are
// multiplied by exactly-zero weights. Mask is pre-folded into wgt.
// ---------------------------------------------------------------------------
__global__ __launch_bounds__(256) void iter4(
    const __half* __restrict__ wgt, const float* __restrict__ xin,
    float* __restrict__ xout)
{
    int gid = blockIdx.x * 256 + threadIdx.x;
    int p0 = gid * 4;                      // grid sized exactly
    int b   = p0 / HW;
    int rem = p0 - b * HW;                 // multiple of 4
    const size_t bHW = (size_t)b * HW;

    const float*  xb = xin + bHW;
    const __half* wb = wgt + (size_t)b * K2 * HW + rem;

    float acc[4] = {0, 0, 0, 0};
#pragma unroll
    for (int dr = -2; dr <= 2; ++dr) {
        // x row h+dr, cols c0-4 .. c0+7, three aligned float4 loads
        const float* p = xb + rem + dr * WW - 4;
        float xs[12];
#pragma unroll
        for (int q = 0; q < 3; ++q) {
            float4 v = *(const float4*)(p + 4 * q);
            xs[4 * q + 0] = v.x; xs[4 * q + 1] = v.y;
            xs[4 * q + 2] = v.z; xs[4 * q + 3] = v.w;
        }
#pragma unroll
        for (int dc = 0; dc < 5; ++dc) {
            const int t = (dr + 2) * 5 + dc;
            float2 wv2 = *(const float2*)(wb + (size_t)t * HW);  // 4 halves
            const __half2* hp = (const __half2*)&wv2;
            float2 w01 = __half22float2(hp[0]);
            float2 w23 = __half22float2(hp[1]);
            acc[0] = fmaf(w01.x, xs[dc + 2], acc[0]);
            acc[1] = fmaf(w01.y, xs[dc + 3], acc[1]);
            acc[2] = fmaf(w23.x, xs[dc + 4], acc[2]);
            acc[3] = fmaf(w23.y, xs[dc + 5], acc[3]);
        }
    }
    *(float4*)(xout + bHW + rem) = make_float4(acc[0], acc[1], acc[2], acc[3]);
}

extern "C" void kernel_launch(void* const* d_in, const int* in_sizes, int n_in,
                              void* d_out, int out_size, void* d_ws, size_t ws_size,
                              hipStream_t stream)
{
    const float* img  = (const float*)d_in[0];
    const float* feat = (const float*)d_in[1];
    const float* mask = (const float*)d_in[2];
    float* out = (float*)d_out;

    // ws layout: [ wgt: B*25*HW halves (~29.5 MB) | PADF | xa | PADF | xb | PADF ]
    __half* wgt = (__half*)d_ws;
    float* fbase = (float*)((char*)d_ws + (((size_t)BB * K2 * HW * sizeof(__half) + 255) & ~(size_t)255));
    float* xa = fbase + PADF;
    float* xb = xa + (size_t)BB * HW + PADF;

    const int n = BB * HW;
    prep2<<<(n / 2 + 255) / 256, 256, 0, stream>>>(img, feat, mask, wgt, xa);

    const int iblocks = n / 4 / 256;   // 576, exact
    float* cur = xa;
    float* nxt = xb;
    for (int it = 0; it < NITER - 1; ++it) {
        iter4<<<iblocks, 256, 0, stream>>>(wgt, cur, nxt);
        float* t = cur; cur = nxt; nxt = t;
    }
    iter4<<<iblocks, 256, 0, stream>>>(wgt, cur, out);
}